// Round 5
// baseline (250.089 us; speedup 1.0000x reference)
//
#include <hip/hip_runtime.h>
#include <cstdint>
#include <cmath>

typedef unsigned short u16;
typedef u16   u16x4  __attribute__((ext_vector_type(4)));
typedef u16   u16x8  __attribute__((ext_vector_type(8)));
typedef __bf16 bf16x8 __attribute__((ext_vector_type(8)));
typedef float f32x4  __attribute__((ext_vector_type(4)));

__device__ __forceinline__ u16 f2bf(float f) {
    uint32_t u = __builtin_bit_cast(uint32_t, f);
    u += 0x7fffu + ((u >> 16) & 1u);   // round-to-nearest-even
    return (u16)(u >> 16);
}
__device__ __forceinline__ float bf2f(u16 v) {
    uint32_t u = ((uint32_t)v) << 16;
    return __builtin_bit_cast(float, u);
}
// async global->LDS, 16B per lane. LDS dest is wave-uniform base + lane*16.
__device__ __forceinline__ void gload_lds16(const u16* g, u16* l) {
    __builtin_amdgcn_global_load_lds((const __attribute__((address_space(1))) void*)g,
                                     (__attribute__((address_space(3))) void*)l,
                                     16, 0, 0);
}

// ---- prep: cast X fp32->bf16  +  transpose-cast W -> Wt[N][K] bf16 ----
__global__ __launch_bounds__(256) void prep_kernel(const float* __restrict__ X,
                                                   const float* __restrict__ Wq,
                                                   const float* __restrict__ Wk,
                                                   const float* __restrict__ Wv,
                                                   u16* __restrict__ Xb,
                                                   u16* __restrict__ Wt) {
    __shared__ u16 tile[64 * 72];
    typedef float f4 __attribute__((ext_vector_type(4)));
    const int bid = blockIdx.x;
    if (bid < 8192) {                       // cast X: 8192 blocks * 256 thr * 4 elems
        const int idx = bid * 256 + threadIdx.x;
        f4 f = ((const f4*)X)[idx];
        u16x4 o;
        o[0] = f2bf(f[0]); o[1] = f2bf(f[1]); o[2] = f2bf(f[2]); o[3] = f2bf(f[3]);
        ((u16x4*)Xb)[idx] = o;
        return;
    }
    const int id = bid - 8192;              // 768 blocks: W transpose-cast
    const int z = id >> 8, rem = id & 255;
    const float* W = (z == 0) ? Wq : (z == 1) ? Wk : Wv;
    u16* out = Wt + ((size_t)z << 20);
    const int nt = (rem & 15) * 64, kt = (rem >> 4) * 64;
    const int t = threadIdx.x, r = t >> 2, cq = (t & 3) * 16;
    const float* src = W + (size_t)(kt + r) * 1024 + nt + cq;
#pragma unroll
    for (int q = 0; q < 4; q++) {
        f4 f = ((const f4*)src)[q];
        tile[r * 72 + cq + q * 4 + 0] = f2bf(f[0]);
        tile[r * 72 + cq + q * 4 + 1] = f2bf(f[1]);
        tile[r * 72 + cq + q * 4 + 2] = f2bf(f[2]);
        tile[r * 72 + cq + q * 4 + 3] = f2bf(f[3]);
    }
    __syncthreads();
    u16x8 o0, o1;
#pragma unroll
    for (int e = 0; e < 8; e++) { o0[e] = tile[(cq + e) * 72 + r]; o1[e] = tile[(cq + 8 + e) * 72 + r]; }
    u16* dst = out + (size_t)(nt + r) * 1024 + kt + cq;
    *(u16x8*)dst = o0;
    *(u16x8*)(dst + 8) = o1;
}

// ------------- shared GEMM core: C[M,N] (+)= A[M,K_rng] * Bt[N,K_rng]^T -------------
// 128x128 tile, BK=32, 256 threads = 4 waves (2x2), 4x4 16x16x32 MFMA tiles/wave.
// LDS K-chunk XOR swizzle (R7: verified SQ_LDS_BANK_CONFLICT 6.3M -> 0).
// OUTMODE: 0 = bf16 store, 1 = f32 store. Output origin (om0,on0) decoupled from input.
template <int OUTMODE>
__device__ __forceinline__ void gemm_bt_core(u16* __restrict__ smem,
                                             const u16* __restrict__ A,
                                             const u16* __restrict__ Bt,
                                             void* __restrict__ outp,
                                             const int ldk, const int ldo,
                                             const int kbeg, const int kend,
                                             const int m0, const int n0,
                                             const int om0, const int on0) {
    u16* As = smem;            // [128][32]
    u16* Bs = smem + 4096;     // [128][32]
    const int tid = (int)threadIdx.x;
    const int wave = tid >> 6, lane = tid & 63;
    const int wm = wave >> 1, wn = wave & 1;

    f32x4 acc[4][4] = {};

    const int sr = lane >> 2;                                  // staging row in 16-row group
    const int scw = ((lane & 3) ^ ((sr >> 1) & 3)) * 8;        // XOR-swizzled global col chunk
    const u16* gA = A  + (size_t)(m0 + wave * 32 + sr) * ldk + scw;
    const u16* gB = Bt + (size_t)(n0 + wave * 32 + sr) * ldk + scw;
    u16* lA = As + wave * 1024;          // wave-uniform LDS base
    u16* lB = Bs + wave * 1024;
    const size_t rstep = (size_t)ldk * 16;   // +16 rows: swizzle bits unchanged

    const int arow = lane & 15;
    const int ksw  = (arow >> 1) & 3;                          // same swizzle bits on read side
    const int koff = (((lane >> 4) ^ ksw)) * 8;
    const u16* pa = As + (wm * 64 + arow) * 32 + koff;
    const u16* pb = Bs + (wn * 64 + arow) * 32 + koff;

    for (int k0 = kbeg; k0 < kend; k0 += 32) {
        gload_lds16(gA + k0,         lA);
        gload_lds16(gA + k0 + rstep, lA + 512);
        gload_lds16(gB + k0,         lB);
        gload_lds16(gB + k0 + rstep, lB + 512);
        __syncthreads();
        bf16x8 a[4], b[4];
#pragma unroll
        for (int i = 0; i < 4; i++) a[i] = *(const bf16x8*)(pa + i * 512);
#pragma unroll
        for (int j = 0; j < 4; j++) b[j] = *(const bf16x8*)(pb + j * 512);
#pragma unroll
        for (int i = 0; i < 4; i++)
#pragma unroll
            for (int j = 0; j < 4; j++)
                acc[i][j] = __builtin_amdgcn_mfma_f32_16x16x32_bf16(a[i], b[j], acc[i][j], 0, 0, 0);
        __syncthreads();
    }

    // epilogue: C/D layout col=lane&15, row=(lane>>4)*4+reg  [m89/m91-verified]
    const int row0 = om0 + wm * 64 + ((lane >> 4) << 2);
    const int col0 = on0 + wn * 64 + (lane & 15);
    if constexpr (OUTMODE == 0) {
        u16* o = (u16*)outp;
#pragma unroll
        for (int i = 0; i < 4; i++)
#pragma unroll
            for (int r = 0; r < 4; r++) {
                u16* po = o + (size_t)(row0 + i * 16 + r) * ldo + col0;
#pragma unroll
                for (int j = 0; j < 4; j++) po[j * 16] = f2bf(acc[i][j][r]);
            }
    } else {
        float* o = (float*)outp;
#pragma unroll
        for (int i = 0; i < 4; i++)
#pragma unroll
            for (int r = 0; r < 4; r++) {
                float* po = o + (size_t)(row0 + i * 16 + r) * ldo + col0;
#pragma unroll
                for (int j = 0; j < 4; j++) po[j * 16] = acc[i][j][r];
            }
    }
}

// ====================== QKV GEMM: 256x128 balanced quadrant template (R12) ======================
// X[8192,1024] * Wt[z][1024,1024]^T -> QKV[z][8192,1024] bf16.
// R12: z-SPLIT into 3 dispatches of exactly 256 blocks (1 exact round each); z baked via
// pointer offsets in kernel_launch. Body identical to R10 (62.9 us best / 819 TF / 0 conflicts).
// Purpose: each dispatch ~21 us < s_tr/pv -> rocprof top-5 finally surfaces s_tr/pv durations
// + inter-dispatch gap timestamps (the ~70 us unexplained residual localizes this round).
// Structure: 512 thr (8 waves 2Mx4N), BK=64, 2-deep dbuf, 2 phases/K-tile over A-halves,
// counted vmcnt(6), setprio around MFMA, global-source XOR swizzle. See R3 notes.
__global__ __launch_bounds__(512, 2) void qkv_gemm_kernel(const u16* __restrict__ Xb,
                                                          const u16* __restrict__ B,
                                                          u16* __restrict__ C) {
    __shared__ u16 lds[49152];   // 96 KiB: A[buf0|buf1] 32K u16 | B[buf0|buf1] 16K u16
    const int bid = blockIdx.x;                  // 0..255
    const int xcd = bid & 7, s = bid >> 3;       // 32 slots/XCD
    const int m0 = (xcd * 4 + (s >> 3)) << 8;    // 4 M-tiles of 256 per XCD
    const int n0 = (s & 7) << 7;                 // 8 N-tiles of 128

    const u16* __restrict__ A = Xb;

    const int tid = (int)threadIdx.x;
    const int w = tid >> 6, l = tid & 63;
    const int wm = w >> 2, wn = w & 3;           // 2 x 4 wave grid

    // ---- staging addressing: one gload issue = 64 rows (8 rows/wave, 128 B each) ----
    const int srow = w * 16 + (l >> 3);
    const int scol = ((l & 7) ^ ((l >> 3) & 7)) * 8;          // pre-swizzled source chunk
    const u16* gA = A + (size_t)(m0 + srow) * 1024 + scol;
    const u16* gB = B + (size_t)(n0 + srow) * 1024 + scol;
    u16* const sA = lds + w * 1024;                           // wave-uniform dests
    u16* const sB = lds + 32768 + w * 1024;

    // ---- fragment read addressing (swizzle re-applied: chunk ^ (row&7), row&7 == l&7) ----
    const int c0 = ((l >> 4) ^ (l & 7)) * 8;                  // k-step 0 chunk; step 1: c0^32
    const u16* const pa_ = lds + (wm * 64 + (l & 15)) * 64;
    const u16* const pb_ = lds + 32768 + (wn * 32 + (l & 15)) * 64;

    f32x4 acc[2][4][2] = {};    // [qa][m][n]
    bf16x8 a[4][2], b[2][2];

#define MFMA_ __builtin_amdgcn_mfma_f32_16x16x32_bf16
#define STG_A(BUF, H, T) \
    gload_lds16(gA + (size_t)((H) * 128) * 1024 + (T) * 64,       sA + (BUF) + (H) * 8192); \
    gload_lds16(gA + (size_t)((H) * 128 + 8) * 1024 + (T) * 64,   sA + (BUF) + (H) * 8192 + 512);
#define STG_B(BUF, T) \
    gload_lds16(gB + (T) * 64,                                    sB + ((BUF) >> 1)); \
    gload_lds16(gB + (size_t)8 * 1024 + (T) * 64,                 sB + ((BUF) >> 1) + 512);
#define LD_A(BUF, QA) \
    _Pragma("unroll") for (int m_ = 0; m_ < 4; m_++) { \
        a[m_][0] = *(const bf16x8*)(pa_ + (BUF) + (QA) * 8192 + m_ * 1024 + c0); \
        a[m_][1] = *(const bf16x8*)(pa_ + (BUF) + (QA) * 8192 + m_ * 1024 + (c0 ^ 32)); \
    }
#define LD_B(BUF) \
    _Pragma("unroll") for (int n_ = 0; n_ < 2; n_++) { \
        b[n_][0] = *(const bf16x8*)(pb_ + ((BUF) >> 1) + n_ * 1024 + c0); \
        b[n_][1] = *(const bf16x8*)(pb_ + ((BUF) >> 1) + n_ * 1024 + (c0 ^ 32)); \
    }
#define MM(QA) \
    _Pragma("unroll") for (int m_ = 0; m_ < 4; m_++) { \
        _Pragma("unroll") for (int n_ = 0; n_ < 2; n_++) { \
            acc[QA][m_][n_] = MFMA_(a[m_][0], b[n_][0], acc[QA][m_][n_], 0, 0, 0); \
            acc[QA][m_][n_] = MFMA_(a[m_][1], b[n_][1], acc[QA][m_][n_], 0, 0, 0); \
        } \
    }
#define VM6 asm volatile("s_waitcnt vmcnt(6)" ::: "memory");
#define VM2 asm volatile("s_waitcnt vmcnt(2)" ::: "memory");
#define VM0 asm volatile("s_waitcnt vmcnt(0)" ::: "memory");
#define VMN
#define BAR __builtin_amdgcn_s_barrier();
#define PRIO1 __builtin_amdgcn_s_setprio(1);
#define PRIO0 __builtin_amdgcn_s_setprio(0);
// One K-tile = 2 phases. ds_read_b128 per phase: 12 / 8. Stage issues: p1 +2, p2 +4.
#define TILE(BUF, OBUF, T1, S1, T2, S2, VMA, VMB) \
    LD_A(BUF, 0) LD_B(BUF) \
    if (S1) { STG_A(OBUF, 1, T1) } \
    VMA BAR PRIO1 MM(0) PRIO0 BAR \
    LD_A(BUF, 1) \
    if (S2) { STG_A(BUF, 0, T2) STG_B(BUF, T2) } \
    VMB BAR PRIO1 MM(1) PRIO0 BAR

    // prologue: tile0 {A0,B,A1}, tile1 {A0,B} = 10 issues; vmcnt(6) completes A0(0),B(0),
    // leaving [A1(0), A0(1), B(1)] = 6 in flight = the steady-state invariant.
    STG_A(0, 0, 0) STG_B(0, 0) STG_A(0, 1, 0)
    STG_A(16384, 0, 1) STG_B(16384, 1)
    asm volatile("s_waitcnt vmcnt(6)" ::: "memory");
    __builtin_amdgcn_s_barrier();

    // steady state: tiles 0..13 (pairs); stage A1(t+1) at p1, A0/B(t+2) at p2.
#pragma unroll 1
    for (int i = 0; i < 7; ++i) {
        const int t1 = 2 * i + 1, t2 = 2 * i + 2, t3 = 2 * i + 3;
        TILE(0,     16384, t1, 1, t2, 1, VM6, VM6)   // tile 2i   (buf0)
        TILE(16384, 0,     t2, 1, t3, 1, VM6, VM6)   // tile 2i+1 (buf1)
    }
    // drain: t=14 stages A1(15) then completes A0/B(15) via VM2; t=15 completes A1(15) via VM0.
    TILE(0,     16384, 15, 1, 0, 0, VM6, VM2)
    TILE(16384, 0,     0,  0, 0, 0, VM0, VMN)

    // epilogue: C/D layout col=lane&15, row=(lane>>4)*4+reg  [m89/m91-verified]
    const int row0 = m0 + wm * 64 + ((l >> 4) << 2);
    const int col0 = n0 + wn * 32 + (l & 15);
#pragma unroll
    for (int qa = 0; qa < 2; qa++)
#pragma unroll
        for (int m = 0; m < 4; m++)
#pragma unroll
            for (int r = 0; r < 4; r++) {
                u16* po = C + (size_t)(row0 + qa * 128 + m * 16 + r) * 1024 + col0;
#pragma unroll
                for (int n = 0; n < 2; n++) po[n * 16] = f2bf(acc[qa][m][n][r]);
            }
#undef MFMA_
#undef STG_A
#undef STG_B
#undef LD_A
#undef LD_B
#undef MM
#undef VM6
#undef VM2
#undef VM0
#undef VMN
#undef BAR
#undef PRIO1
#undef PRIO0
#undef TILE
}

// fused: S = Q*K^T (causal tiles, XCD-banded)  +  V transpose (2048 blocks).
// GEMM tiles banded: XCD = (b<<1)|half; half 0 = it 0..10 (66 tiles), half 1 =
// it 11..15 (70 tiles); 72 slots each (few idle). Working set ~5.5 MB/XCD vs
// the old full-scatter ~8 MB/batch across all XCDs (R5 FETCH 110 MB).
__global__ __launch_bounds__(256) void s_tr_kernel(const u16* __restrict__ QKV,
                                                   u16* __restrict__ S,
                                                   u16* __restrict__ Vt) {
    __shared__ u16 smem[8192];
    const int bid = blockIdx.x;
    if (bid < 576) {
        const int xcd = bid & 7, slot = bid >> 3;   // slot 0..71
        const int b = xcd >> 1, half = xcd & 1;
        int it = half ? 11 : 0;
        const int ntiles = half ? 70 : 66;
        if (slot >= ntiles) return;
        int acc = 0;
        while (acc + it + 1 <= slot) { acc += it + 1; it++; }
        const int jt = slot - acc;
        const u16* Q  = QKV + ((size_t)b << 21);
        const u16* Kp = QKV + ((size_t)1 << 23) + ((size_t)b << 21);
        gemm_bt_core<0>(smem, Q, Kp, S + ((size_t)b << 22), 1024, 2048, 0, 1024,
                        it * 128, jt * 128, it * 128, jt * 128);
        return;
    }
    // V[b][s][e] -> Vt[b][e][s], 64x64 tiles
    const int id = bid - 576;
    const int z = id >> 9, rem = id & 511;
    const u16* src = QKV + ((size_t)2 << 23) + ((size_t)z << 21);
    u16* dst = Vt + ((size_t)z << 21);
    const int st = (rem & 31) * 64, et = (rem >> 5) * 64;
    u16 (*tile)[72] = (u16(*)[72])smem;
    const int t = threadIdx.x, r = t >> 2, cq = (t & 3) * 16;
    const u16* p = src + (size_t)(st + r) * 1024 + et + cq;
    u16x8 u0 = *(const u16x8*)p;
    u16x8 u1 = *(const u16x8*)(p + 8);
#pragma unroll
    for (int e = 0; e < 8; e++) { tile[r][cq + e] = u0[e]; tile[r][cq + 8 + e] = u1[e]; }
    __syncthreads();
    u16x8 o0, o1;
#pragma unroll
    for (int e = 0; e < 8; e++) { o0[e] = tile[cq + e][r]; o1[e] = tile[cq + 8 + e][r]; }
    u16* q = dst + (size_t)(et + r) * 2048 + st + cq;
    *(u16x8*)q = o0;
    *(u16x8*)(q + 8) = o1;
}

// O = P * Vt^T — complementary-pair scheduling, NO split-K (R11).
// Causal K-length for row-tile it is (it+1) K128-units; pairs (it, 15-it) sum to a
// constant 17 units. 512 blocks (all co-resident: 4 waves, 16 KB LDS -> 2/CU):
// block c and c+256 carry complementary its for the same (b, n0) spread, so every CU
// hosts ~17 units regardless of which pair member it gets — same dispatch-index
// co-location assumption as the old CU-triple table, but with PLAIN f32 stores:
// no Part buffer, no reduce kernel, no atomics, fully deterministic.
__global__ __launch_bounds__(256) void pv_gemm_kernel(const u16* __restrict__ P,
                                                      const u16* __restrict__ Vt,
                                                      float* __restrict__ O) {
    __shared__ u16 smem[8192];
    const int j = blockIdx.x;                 // 0..511
    const int phase = j >> 8, c = j & 255;    // phase 0: blocks 0..255, phase 1: 256..511
    const int slot = c >> 5, combo = c & 31;  // slot 0..7, combo 0..31
    const int it = phase ? (15 - slot) : slot;
    const int b = combo >> 3, n0 = (combo & 7) * 128;
    gemm_bt_core<1>(smem, P + ((size_t)b << 22), Vt + ((size_t)b << 21),
                    O + ((size_t)b << 21),
                    2048, 1024, 0, (it + 1) * 128, it * 128, n0, it * 128, n0);
}

// --------- in-place causal softmax (scale 1/32), truncated to kend=((i>>7)+1)*128 ---------
__global__ __launch_bounds__(256) void softmax_kernel(u16* __restrict__ S) {
    const int wave = threadIdx.x >> 6, lane = threadIdx.x & 63;
    const int g = blockIdx.x * 4 + wave;       // 0..8191
    const int b = g >> 11, i = g & 2047;
    u16* row = S + ((size_t)b << 22) + ((size_t)i << 11);
    const int n = i + 1;                        // valid keys
    const int kend = ((i >> 7) + 1) << 7;       // pv reads cols [0, kend)
    const int nt_ = (kend + 511) >> 9;          // active 512-col chunks (1..4), wave-uniform
    const float NEG = -1e30f;
    float v[32];
    float m = NEG;
#pragma unroll
    for (int t = 0; t < 4; t++) {
        if (t < nt_) {
            u16x8 u = *(const u16x8*)(row + t * 512 + lane * 8);
#pragma unroll
            for (int e = 0; e < 8; e++) {
                const int col = t * 512 + lane * 8 + e;
                float f = (col < n) ? bf2f(u[e]) : NEG;
                v[t * 8 + e] = f;
                m = fmaxf(m, f);
            }
        }
    }
#pragma unroll
    for (int off = 32; off > 0; off >>= 1) m = fmaxf(m, __shfl_xor(m, off, 64));
    const float sc = 0.03125f * 1.44269504088896f;   // (1/sqrt(1024)) * log2(e)
    float s = 0.f;
#pragma unroll
    for (int t = 0; t < 4; t++) {
        if (t < nt_) {
#pragma unroll
            for (int e = 0; e < 8; e++) {
                const float x = v[t * 8 + e];
                const float e2 = (x == NEG) ? 0.f : exp2f((x - m) * sc);
                v[t * 8 + e] = e2;
                s += e2;
            }
        }
    }
#pragma unroll
    for (int off = 32; off > 0; off >>= 1) s += __shfl_xor(s, off, 64);
    const float inv = 1.f / s;
#pragma unroll
    for (int t = 0; t < 4; t++) {
        if (t < nt_) {
            u16x8 o;
#pragma unroll
            for (int e = 0; e < 8; e++) o[e] = f2bf(v[t * 8 + e] * inv);
            *(u16x8*)(row + t * 512 + lane * 8) = o;
        }
    }
}

extern "C" void kernel_launch(void* const* d_in, const int* in_sizes, int n_in,
                              void* d_out, int out_size, void* d_ws, size_t ws_size,
                              hipStream_t stream) {
    const float* X  = (const float*)d_in[0];
    const float* Wq = (const float*)d_in[1];
    const float* Wk = (const float*)d_in[2];
    const float* Wv = (const float*)d_in[3];
    float* out = (float*)d_out;

    // ws layout (u16 elems): Xb 8M | Wt 3M | QKV 24M | S 16M  -> ~102 MB
    u16* ws  = (u16*)d_ws;
    u16* Xb  = ws;                                   // 1<<23 elems (reused as Vt)
    u16* Wt  = Xb + ((size_t)1 << 23);               // 3 * (1<<20)
    u16* QKV = Wt + 3 * ((size_t)1 << 20);           // 3 * (1<<23)
    u16* S   = QKV + 3 * ((size_t)1 << 23);          // 1<<24
    u16* Vt  = Xb;                                   // Xb dead after QKV GEMM

    prep_kernel<<<8960, 256, 0, stream>>>(X, Wq, Wk, Wv, Xb, Wt);
    for (int z = 0; z < 3; ++z)
        qkv_gemm_kernel<<<256, 512, 0, stream>>>(Xb, Wt + ((size_t)z << 20),
                                                 QKV + ((size_t)z << 23));
    s_tr_kernel<<<2624, 256, 0, stream>>>(QKV, S, Vt);
    softmax_kernel<<<2048, 256, 0, stream>>>(S);
    pv_gemm_kernel<<<512, 256, 0, stream>>>(S, Vt, out);
}

// Round 6
// 219.001 us; speedup vs baseline: 1.1420x; 1.1420x over previous
//
#include <hip/hip_runtime.h>
#include <cstdint>
#include <cmath>

typedef unsigned short u16;
typedef u16   u16x4  __attribute__((ext_vector_type(4)));
typedef u16   u16x8  __attribute__((ext_vector_type(8)));
typedef __bf16 bf16x8 __attribute__((ext_vector_type(8)));
typedef float f32x4  __attribute__((ext_vector_type(4)));

__device__ __forceinline__ u16 f2bf(float f) {
    uint32_t u = __builtin_bit_cast(uint32_t, f);
    u += 0x7fffu + ((u >> 16) & 1u);   // round-to-nearest-even
    return (u16)(u >> 16);
}
__device__ __forceinline__ float bf2f(u16 v) {
    uint32_t u = ((uint32_t)v) << 16;
    return __builtin_bit_cast(float, u);
}
// async global->LDS, 16B per lane. LDS dest is wave-uniform base + lane*16.
__device__ __forceinline__ void gload_lds16(const u16* g, u16* l) {
    __builtin_amdgcn_global_load_lds((const __attribute__((address_space(1))) void*)g,
                                     (__attribute__((address_space(3))) void*)l,
                                     16, 0, 0);
}

// ---- prep: cast X fp32->bf16  +  transpose-cast W -> Wt[N][K] bf16 ----
__global__ __launch_bounds__(256) void prep_kernel(const float* __restrict__ X,
                                                   const float* __restrict__ Wq,
                                                   const float* __restrict__ Wk,
                                                   const float* __restrict__ Wv,
                                                   u16* __restrict__ Xb,
                                                   u16* __restrict__ Wt) {
    __shared__ u16 tile[64 * 72];
    typedef float f4 __attribute__((ext_vector_type(4)));
    const int bid = blockIdx.x;
    if (bid < 8192) {                       // cast X: 8192 blocks * 256 thr * 4 elems
        const int idx = bid * 256 + threadIdx.x;
        f4 f = ((const f4*)X)[idx];
        u16x4 o;
        o[0] = f2bf(f[0]); o[1] = f2bf(f[1]); o[2] = f2bf(f[2]); o[3] = f2bf(f[3]);
        ((u16x4*)Xb)[idx] = o;
        return;
    }
    const int id = bid - 8192;              // 768 blocks: W transpose-cast
    const int z = id >> 8, rem = id & 255;
    const float* W = (z == 0) ? Wq : (z == 1) ? Wk : Wv;
    u16* out = Wt + ((size_t)z << 20);
    const int nt = (rem & 15) * 64, kt = (rem >> 4) * 64;
    const int t = threadIdx.x, r = t >> 2, cq = (t & 3) * 16;
    const float* src = W + (size_t)(kt + r) * 1024 + nt + cq;
#pragma unroll
    for (int q = 0; q < 4; q++) {
        f4 f = ((const f4*)src)[q];
        tile[r * 72 + cq + q * 4 + 0] = f2bf(f[0]);
        tile[r * 72 + cq + q * 4 + 1] = f2bf(f[1]);
        tile[r * 72 + cq + q * 4 + 2] = f2bf(f[2]);
        tile[r * 72 + cq + q * 4 + 3] = f2bf(f[3]);
    }
    __syncthreads();
    u16x8 o0, o1;
#pragma unroll
    for (int e = 0; e < 8; e++) { o0[e] = tile[(cq + e) * 72 + r]; o1[e] = tile[(cq + 8 + e) * 72 + r]; }
    u16* dst = out + (size_t)(nt + r) * 1024 + kt + cq;
    *(u16x8*)dst = o0;
    *(u16x8*)(dst + 8) = o1;
}

// ------------- shared GEMM core: C[M,N] (+)= A[M,K_rng] * Bt[N,K_rng]^T -------------
// 128x128 tile, BK=32, 256 threads = 4 waves (2x2), 4x4 16x16x32 MFMA tiles/wave.
// LDS K-chunk XOR swizzle (R7: verified SQ_LDS_BANK_CONFLICT 6.3M -> 0).
// OUTMODE: 0 = bf16 store, 1 = f32 store. Output origin (om0,on0) decoupled from input.
template <int OUTMODE>
__device__ __forceinline__ void gemm_bt_core(u16* __restrict__ smem,
                                             const u16* __restrict__ A,
                                             const u16* __restrict__ Bt,
                                             void* __restrict__ outp,
                                             const int ldk, const int ldo,
                                             const int kbeg, const int kend,
                                             const int m0, const int n0,
                                             const int om0, const int on0) {
    u16* As = smem;            // [128][32]
    u16* Bs = smem + 4096;     // [128][32]
    const int tid = (int)threadIdx.x;
    const int wave = tid >> 6, lane = tid & 63;
    const int wm = wave >> 1, wn = wave & 1;

    f32x4 acc[4][4] = {};

    const int sr = lane >> 2;                                  // staging row in 16-row group
    const int scw = ((lane & 3) ^ ((sr >> 1) & 3)) * 8;        // XOR-swizzled global col chunk
    const u16* gA = A  + (size_t)(m0 + wave * 32 + sr) * ldk + scw;
    const u16* gB = Bt + (size_t)(n0 + wave * 32 + sr) * ldk + scw;
    u16* lA = As + wave * 1024;          // wave-uniform LDS base
    u16* lB = Bs + wave * 1024;
    const size_t rstep = (size_t)ldk * 16;   // +16 rows: swizzle bits unchanged

    const int arow = lane & 15;
    const int ksw  = (arow >> 1) & 3;                          // same swizzle bits on read side
    const int koff = (((lane >> 4) ^ ksw)) * 8;
    const u16* pa = As + (wm * 64 + arow) * 32 + koff;
    const u16* pb = Bs + (wn * 64 + arow) * 32 + koff;

    for (int k0 = kbeg; k0 < kend; k0 += 32) {
        gload_lds16(gA + k0,         lA);
        gload_lds16(gA + k0 + rstep, lA + 512);
        gload_lds16(gB + k0,         lB);
        gload_lds16(gB + k0 + rstep, lB + 512);
        __syncthreads();
        bf16x8 a[4], b[4];
#pragma unroll
        for (int i = 0; i < 4; i++) a[i] = *(const bf16x8*)(pa + i * 512);
#pragma unroll
        for (int j = 0; j < 4; j++) b[j] = *(const bf16x8*)(pb + j * 512);
#pragma unroll
        for (int i = 0; i < 4; i++)
#pragma unroll
            for (int j = 0; j < 4; j++)
                acc[i][j] = __builtin_amdgcn_mfma_f32_16x16x32_bf16(a[i], b[j], acc[i][j], 0, 0, 0);
        __syncthreads();
    }

    // epilogue: C/D layout col=lane&15, row=(lane>>4)*4+reg  [m89/m91-verified]
    const int row0 = om0 + wm * 64 + ((lane >> 4) << 2);
    const int col0 = on0 + wn * 64 + (lane & 15);
    if constexpr (OUTMODE == 0) {
        u16* o = (u16*)outp;
#pragma unroll
        for (int i = 0; i < 4; i++)
#pragma unroll
            for (int r = 0; r < 4; r++) {
                u16* po = o + (size_t)(row0 + i * 16 + r) * ldo + col0;
#pragma unroll
                for (int j = 0; j < 4; j++) po[j * 16] = f2bf(acc[i][j][r]);
            }
    } else {
        float* o = (float*)outp;
#pragma unroll
        for (int i = 0; i < 4; i++)
#pragma unroll
            for (int r = 0; r < 4; r++) {
                float* po = o + (size_t)(row0 + i * 16 + r) * ldo + col0;
#pragma unroll
                for (int j = 0; j < 4; j++) po[j * 16] = acc[i][j][r];
            }
    }
}

// ====================== QKV GEMM: 256x128 balanced quadrant template (R10/R13) ======================
// X[8192,1024] * Wt[z][1024,1024]^T -> QKV[z][8192,1024] bf16.
// 768 blocks = 3 EXACT rounds (1 block/CU, 96 KiB LDS). Best measured 62.9 us, 819 TF,
// MfmaUtil 32%, 0 conflicts = ~97% of guide's m248 (848 TF @ K=1024) -> at plateau.
// R13: reverted R12's 3x z-split (cost ~+10 us total in launch overhead/lost overlap).
// Structure: 512 thr (8 waves 2Mx4N), BK=64, 2-deep dbuf, 2 phases/K-tile over A-halves,
// counted vmcnt(6), setprio around MFMA, global-source XOR swizzle. See R3 notes.
__global__ __launch_bounds__(512, 2) void qkv_gemm_kernel(const u16* __restrict__ Xb,
                                                          const u16* __restrict__ Wt,
                                                          u16* __restrict__ QKV) {
    __shared__ u16 lds[49152];   // 96 KiB: A[buf0|buf1] 32K u16 | B[buf0|buf1] 16K u16
    const int bid = blockIdx.x;                  // 0..767
    const int xcd = bid & 7, slot = bid >> 3;    // 96 slots/XCD
    const int z = slot >> 5, r32 = slot & 31;    // z-outer: 32 slots per z
    const int m0 = (xcd * 4 + (r32 >> 3)) << 8;  // 4 M-tiles of 256 per XCD
    const int n0 = (r32 & 7) << 7;               // 8 N-tiles of 128

    const u16* __restrict__ A = Xb;
    const u16* __restrict__ B = Wt + ((size_t)z << 20);
    u16* __restrict__ C = QKV + ((size_t)z << 23);

    const int tid = (int)threadIdx.x;
    const int w = tid >> 6, l = tid & 63;
    const int wm = w >> 2, wn = w & 3;           // 2 x 4 wave grid

    // ---- staging addressing: one gload issue = 64 rows (8 rows/wave, 128 B each) ----
    const int srow = w * 16 + (l >> 3);
    const int scol = ((l & 7) ^ ((l >> 3) & 7)) * 8;          // pre-swizzled source chunk
    const u16* gA = A + (size_t)(m0 + srow) * 1024 + scol;
    const u16* gB = B + (size_t)(n0 + srow) * 1024 + scol;
    u16* const sA = lds + w * 1024;                           // wave-uniform dests
    u16* const sB = lds + 32768 + w * 1024;

    // ---- fragment read addressing (swizzle re-applied: chunk ^ (row&7), row&7 == l&7) ----
    const int c0 = ((l >> 4) ^ (l & 7)) * 8;                  // k-step 0 chunk; step 1: c0^32
    const u16* const pa_ = lds + (wm * 64 + (l & 15)) * 64;
    const u16* const pb_ = lds + 32768 + (wn * 32 + (l & 15)) * 64;

    f32x4 acc[2][4][2] = {};    // [qa][m][n]
    bf16x8 a[4][2], b[2][2];

#define MFMA_ __builtin_amdgcn_mfma_f32_16x16x32_bf16
#define STG_A(BUF, H, T) \
    gload_lds16(gA + (size_t)((H) * 128) * 1024 + (T) * 64,       sA + (BUF) + (H) * 8192); \
    gload_lds16(gA + (size_t)((H) * 128 + 8) * 1024 + (T) * 64,   sA + (BUF) + (H) * 8192 + 512);
#define STG_B(BUF, T) \
    gload_lds16(gB + (T) * 64,                                    sB + ((BUF) >> 1)); \
    gload_lds16(gB + (size_t)8 * 1024 + (T) * 64,                 sB + ((BUF) >> 1) + 512);
#define LD_A(BUF, QA) \
    _Pragma("unroll") for (int m_ = 0; m_ < 4; m_++) { \
        a[m_][0] = *(const bf16x8*)(pa_ + (BUF) + (QA) * 8192 + m_ * 1024 + c0); \
        a[m_][1] = *(const bf16x8*)(pa_ + (BUF) + (QA) * 8192 + m_ * 1024 + (c0 ^ 32)); \
    }
#define LD_B(BUF) \
    _Pragma("unroll") for (int n_ = 0; n_ < 2; n_++) { \
        b[n_][0] = *(const bf16x8*)(pb_ + ((BUF) >> 1) + n_ * 1024 + c0); \
        b[n_][1] = *(const bf16x8*)(pb_ + ((BUF) >> 1) + n_ * 1024 + (c0 ^ 32)); \
    }
#define MM(QA) \
    _Pragma("unroll") for (int m_ = 0; m_ < 4; m_++) { \
        _Pragma("unroll") for (int n_ = 0; n_ < 2; n_++) { \
            acc[QA][m_][n_] = MFMA_(a[m_][0], b[n_][0], acc[QA][m_][n_], 0, 0, 0); \
            acc[QA][m_][n_] = MFMA_(a[m_][1], b[n_][1], acc[QA][m_][n_], 0, 0, 0); \
        } \
    }
#define VM6 asm volatile("s_waitcnt vmcnt(6)" ::: "memory");
#define VM2 asm volatile("s_waitcnt vmcnt(2)" ::: "memory");
#define VM0 asm volatile("s_waitcnt vmcnt(0)" ::: "memory");
#define VMN
#define BAR __builtin_amdgcn_s_barrier();
#define PRIO1 __builtin_amdgcn_s_setprio(1);
#define PRIO0 __builtin_amdgcn_s_setprio(0);
// One K-tile = 2 phases. ds_read_b128 per phase: 12 / 8. Stage issues: p1 +2, p2 +4.
#define TILE(BUF, OBUF, T1, S1, T2, S2, VMA, VMB) \
    LD_A(BUF, 0) LD_B(BUF) \
    if (S1) { STG_A(OBUF, 1, T1) } \
    VMA BAR PRIO1 MM(0) PRIO0 BAR \
    LD_A(BUF, 1) \
    if (S2) { STG_A(BUF, 0, T2) STG_B(BUF, T2) } \
    VMB BAR PRIO1 MM(1) PRIO0 BAR

    // prologue: tile0 {A0,B,A1}, tile1 {A0,B} = 10 issues; vmcnt(6) completes A0(0),B(0),
    // leaving [A1(0), A0(1), B(1)] = 6 in flight = the steady-state invariant.
    STG_A(0, 0, 0) STG_B(0, 0) STG_A(0, 1, 0)
    STG_A(16384, 0, 1) STG_B(16384, 1)
    asm volatile("s_waitcnt vmcnt(6)" ::: "memory");
    __builtin_amdgcn_s_barrier();

    // steady state: tiles 0..13 (pairs); stage A1(t+1) at p1, A0/B(t+2) at p2.
#pragma unroll 1
    for (int i = 0; i < 7; ++i) {
        const int t1 = 2 * i + 1, t2 = 2 * i + 2, t3 = 2 * i + 3;
        TILE(0,     16384, t1, 1, t2, 1, VM6, VM6)   // tile 2i   (buf0)
        TILE(16384, 0,     t2, 1, t3, 1, VM6, VM6)   // tile 2i+1 (buf1)
    }
    // drain: t=14 stages A1(15) then completes A0/B(15) via VM2; t=15 completes A1(15) via VM0.
    TILE(0,     16384, 15, 1, 0, 0, VM6, VM2)
    TILE(16384, 0,     0,  0, 0, 0, VM0, VMN)

    // epilogue: C/D layout col=lane&15, row=(lane>>4)*4+reg  [m89/m91-verified]
    const int row0 = m0 + wm * 64 + ((l >> 4) << 2);
    const int col0 = n0 + wn * 32 + (l & 15);
#pragma unroll
    for (int qa = 0; qa < 2; qa++)
#pragma unroll
        for (int m = 0; m < 4; m++)
#pragma unroll
            for (int r = 0; r < 4; r++) {
                u16* po = C + (size_t)(row0 + qa * 128 + m * 16 + r) * 1024 + col0;
#pragma unroll
                for (int n = 0; n < 2; n++) po[n * 16] = f2bf(acc[qa][m][n][r]);
            }
#undef MFMA_
#undef STG_A
#undef STG_B
#undef LD_A
#undef LD_B
#undef MM
#undef VM6
#undef VM2
#undef VM0
#undef VMN
#undef BAR
#undef PRIO1
#undef PRIO0
#undef TILE
}

// fused: S = Q*K^T (causal tiles, XCD-banded)  +  V transpose (2048 blocks).
// GEMM tiles banded: XCD = (b<<1)|half; half 0 = it 0..10 (66 tiles), half 1 =
// it 11..15 (70 tiles); 72 slots each (few idle). Working set ~5.5 MB/XCD vs
// the old full-scatter ~8 MB/batch across all XCDs (R5 FETCH 110 MB).
__global__ __launch_bounds__(256) void s_tr_kernel(const u16* __restrict__ QKV,
                                                   u16* __restrict__ S,
                                                   u16* __restrict__ Vt) {
    __shared__ u16 smem[8192];
    const int bid = blockIdx.x;
    if (bid < 576) {
        const int xcd = bid & 7, slot = bid >> 3;   // slot 0..71
        const int b = xcd >> 1, half = xcd & 1;
        int it = half ? 11 : 0;
        const int ntiles = half ? 70 : 66;
        if (slot >= ntiles) return;
        int acc = 0;
        while (acc + it + 1 <= slot) { acc += it + 1; it++; }
        const int jt = slot - acc;
        const u16* Q  = QKV + ((size_t)b << 21);
        const u16* Kp = QKV + ((size_t)1 << 23) + ((size_t)b << 21);
        gemm_bt_core<0>(smem, Q, Kp, S + ((size_t)b << 22), 1024, 2048, 0, 1024,
                        it * 128, jt * 128, it * 128, jt * 128);
        return;
    }
    // V[b][s][e] -> Vt[b][e][s], 64x64 tiles
    const int id = bid - 576;
    const int z = id >> 9, rem = id & 511;
    const u16* src = QKV + ((size_t)2 << 23) + ((size_t)z << 21);
    u16* dst = Vt + ((size_t)z << 21);
    const int st = (rem & 31) * 64, et = (rem >> 5) * 64;
    u16 (*tile)[72] = (u16(*)[72])smem;
    const int t = threadIdx.x, r = t >> 2, cq = (t & 3) * 16;
    const u16* p = src + (size_t)(st + r) * 1024 + et + cq;
    u16x8 u0 = *(const u16x8*)p;
    u16x8 u1 = *(const u16x8*)(p + 8);
#pragma unroll
    for (int e = 0; e < 8; e++) { tile[r][cq + e] = u0[e]; tile[r][cq + 8 + e] = u1[e]; }
    __syncthreads();
    u16x8 o0, o1;
#pragma unroll
    for (int e = 0; e < 8; e++) { o0[e] = tile[cq + e][r]; o1[e] = tile[cq + 8 + e][r]; }
    u16* q = dst + (size_t)(et + r) * 2048 + st + cq;
    *(u16x8*)q = o0;
    *(u16x8*)(q + 8) = o1;
}

// ====================== PV GEMM: 128x128 3-buffer counted-vmcnt core (R13) ======================
// O[it*128..+128][n0..+128] = P[128 x (it+1)*128] * Vt[n0..+128][0..(it+1)*128]^T, f32 out.
// 8 waves (2Mx4N, 64x32/wave), BK=64, 16 MFMA / 12 ds_read per barrier-pair (qkv-grade
// amortization). 3-buffer LDS rotation (96 KiB): tile t reads buf t%3, stages t+2 into
// (t+2)%3 (never the live buffer); steady vmcnt(4) = next tile's 4 issues stay in flight,
// vmcnt(0) only at drain. Deterministic balance: each block runs BOTH causal pair members
// (it, 15-it) sequentially -> K-sum 2176 const; 8 pairs x 8 n0 x 4 b = 256 blocks = 1 exact
// round (no split-K, no Part/reduce, no co-residency assumptions). XCD x owns pair x
// (all b, n0): its two P panels = 2.2 MB, L2-resident.
// S cols beyond a row's causal end are zero up to the 512 boundary (softmax contract),
// and tile it reads exactly (it+1)*128 <= that boundary.
__device__ __forceinline__ void pv_tile128(const u16* __restrict__ Pb,
                                           const u16* __restrict__ Vb,
                                           float* __restrict__ Ob,
                                           u16* __restrict__ lds,
                                           const int it, const int n0) {
    const int tid = (int)threadIdx.x;
    const int w = tid >> 6, l = tid & 63;
    const int wm = w >> 2, wn = w & 3;           // 2 x 4 wave grid
    const int nk = 2 * (it + 1);                 // BK=64 K-tiles (2..32, even)
    const int m0 = it * 128;

    // staging: issue (w,q) covers rows w*16+q*8+(l>>3); pre-swizzled source col
    const int srow = w * 16 + (l >> 3);
    const int scol = ((l & 7) ^ ((l >> 3) & 7)) * 8;
    const u16* gA = Pb + (size_t)(m0 + srow) * 2048 + scol;
    const u16* gB = Vb + (size_t)(n0 + srow) * 2048 + scol;
    u16* const sA = lds + w * 1024;              // within 8192-u16 buffer
    u16* const sB = lds + 24576 + w * 1024;

    // fragment reads: swizzle re-applied (chunk ^ (row&7), row&7 == l&7)
    const int c0 = ((l >> 4) ^ (l & 7)) * 8;
    const u16* const pa_ = lds + (wm * 64 + (l & 15)) * 64;
    const u16* const pb_ = lds + 24576 + (wn * 32 + (l & 15)) * 64;

    f32x4 acc[4][2] = {};

#define PSTG(T, BUF) \
    gload_lds16(gA + (size_t)(T) * 64,                    sA + (BUF) * 8192); \
    gload_lds16(gA + (size_t)(T) * 64 + (size_t)8 * 2048, sA + (BUF) * 8192 + 512); \
    gload_lds16(gB + (size_t)(T) * 64,                    sB + (BUF) * 8192); \
    gload_lds16(gB + (size_t)(T) * 64 + (size_t)8 * 2048, sB + (BUF) * 8192 + 512);

    // prologue: tiles 0,1 (8 issues); vmcnt(4) completes tile0, leaves tile1 in flight
    PSTG(0, 0) PSTG(1, 1)
    asm volatile("s_waitcnt vmcnt(4)" ::: "memory");
    __builtin_amdgcn_s_barrier();

    int bufR = 0, bufW = 2;
#pragma unroll 1
    for (int t = 0; t < nk; ++t) {
        bf16x8 a[4][2], b[2][2];
#pragma unroll
        for (int m = 0; m < 4; m++) {
            a[m][0] = *(const bf16x8*)(pa_ + bufR * 8192 + m * 1024 + c0);
            a[m][1] = *(const bf16x8*)(pa_ + bufR * 8192 + m * 1024 + (c0 ^ 32));
        }
#pragma unroll
        for (int n = 0; n < 2; n++) {
            b[n][0] = *(const bf16x8*)(pb_ + bufR * 8192 + n * 1024 + c0);
            b[n][1] = *(const bf16x8*)(pb_ + bufR * 8192 + n * 1024 + (c0 ^ 32));
        }
        if (t < nk - 2) {
            PSTG(t + 2, bufW)
            asm volatile("s_waitcnt vmcnt(4)" ::: "memory");
        } else {
            asm volatile("s_waitcnt vmcnt(0)" ::: "memory");
        }
        __builtin_amdgcn_s_barrier();
        __builtin_amdgcn_s_setprio(1);
#pragma unroll
        for (int m = 0; m < 4; m++)
#pragma unroll
            for (int n = 0; n < 2; n++) {
                acc[m][n] = __builtin_amdgcn_mfma_f32_16x16x32_bf16(a[m][0], b[n][0], acc[m][n], 0, 0, 0);
                acc[m][n] = __builtin_amdgcn_mfma_f32_16x16x32_bf16(a[m][1], b[n][1], acc[m][n], 0, 0, 0);
            }
        __builtin_amdgcn_s_setprio(0);
        __builtin_amdgcn_s_barrier();
        bufR = (bufR == 2) ? 0 : bufR + 1;
        bufW = (bufW == 2) ? 0 : bufW + 1;
    }
#undef PSTG

    // epilogue: C/D layout col=lane&15, row=(lane>>4)*4+reg
    const int row0 = m0 + wm * 64 + ((l >> 4) << 2);
    const int col0 = n0 + wn * 32 + (l & 15);
#pragma unroll
    for (int m = 0; m < 4; m++)
#pragma unroll
        for (int r = 0; r < 4; r++) {
            float* po = Ob + (size_t)(row0 + m * 16 + r) * 1024 + col0;
#pragma unroll
            for (int n = 0; n < 2; n++) po[n * 16] = acc[m][n][r];
        }
}

__global__ __launch_bounds__(512, 2) void pv_gemm_kernel(const u16* __restrict__ P,
                                                         const u16* __restrict__ Vt,
                                                         float* __restrict__ O) {
    __shared__ u16 lds[49152];   // 96 KiB: A 3x8192 u16 | B 3x8192 u16
    const int bid = blockIdx.x;                  // 0..255
    const int xcd = bid & 7, slot = bid >> 3;    // 32 slots/XCD
    const int combo = xcd * 4 + (slot >> 3);     // (pair,b): XCD x -> pair x, b 0..3
    const int n0 = (slot & 7) * 128;
    const int pair = combo >> 2, b = combo & 3;
    const u16* Pb = P + ((size_t)b << 22);
    const u16* Vb = Vt + ((size_t)b << 21);
    float* Ob = O + ((size_t)b << 21);
    pv_tile128(Pb, Vb, Ob, lds, 15 - pair, n0);  // long member first
    pv_tile128(Pb, Vb, Ob, lds, pair, n0);       // short member (K-sum 2176 const)
}

// --------- in-place causal softmax (scale 1/32), truncated to kend=((i>>7)+1)*128 ---------
__global__ __launch_bounds__(256) void softmax_kernel(u16* __restrict__ S) {
    const int wave = threadIdx.x >> 6, lane = threadIdx.x & 63;
    const int g = blockIdx.x * 4 + wave;       // 0..8191
    const int b = g >> 11, i = g & 2047;
    u16* row = S + ((size_t)b << 22) + ((size_t)i << 11);
    const int n = i + 1;                        // valid keys
    const int kend = ((i >> 7) + 1) << 7;       // pv reads cols [0, kend)
    const int nt_ = (kend + 511) >> 9;          // active 512-col chunks (1..4), wave-uniform
    const float NEG = -1e30f;
    float v[32];
    float m = NEG;
#pragma unroll
    for (int t = 0; t < 4; t++) {
        if (t < nt_) {
            u16x8 u = *(const u16x8*)(row + t * 512 + lane * 8);
#pragma unroll
            for (int e = 0; e < 8; e++) {
                const int col = t * 512 + lane * 8 + e;
                float f = (col < n) ? bf2f(u[e]) : NEG;
                v[t * 8 + e] = f;
                m = fmaxf(m, f);
            }
        }
    }
#pragma unroll
    for (int off = 32; off > 0; off >>= 1) m = fmaxf(m, __shfl_xor(m, off, 64));
    const float sc = 0.03125f * 1.44269504088896f;   // (1/sqrt(1024)) * log2(e)
    float s = 0.f;
#pragma unroll
    for (int t = 0; t < 4; t++) {
        if (t < nt_) {
#pragma unroll
            for (int e = 0; e < 8; e++) {
                const float x = v[t * 8 + e];
                const float e2 = (x == NEG) ? 0.f : exp2f((x - m) * sc);
                v[t * 8 + e] = e2;
                s += e2;
            }
        }
    }
#pragma unroll
    for (int off = 32; off > 0; off >>= 1) s += __shfl_xor(s, off, 64);
    const float inv = 1.f / s;
#pragma unroll
    for (int t = 0; t < 4; t++) {
        if (t < nt_) {
            u16x8 o;
#pragma unroll
            for (int e = 0; e < 8; e++) o[e] = f2bf(v[t * 8 + e] * inv);
            *(u16x8*)(row + t * 512 + lane * 8) = o;
        }
    }
}

extern "C" void kernel_launch(void* const* d_in, const int* in_sizes, int n_in,
                              void* d_out, int out_size, void* d_ws, size_t ws_size,
                              hipStream_t stream) {
    const float* X  = (const float*)d_in[0];
    const float* Wq = (const float*)d_in[1];
    const float* Wk = (const float*)d_in[2];
    const float* Wv = (const float*)d_in[3];
    float* out = (float*)d_out;

    // ws layout (u16 elems): Xb 8M | Wt 3M | QKV 24M | S 16M  -> ~102 MB
    u16* ws  = (u16*)d_ws;
    u16* Xb  = ws;                                   // 1<<23 elems (reused as Vt)
    u16* Wt  = Xb + ((size_t)1 << 23);               // 3 * (1<<20)
    u16* QKV = Wt + 3 * ((size_t)1 << 20);           // 3 * (1<<23)
    u16* S   = QKV + 3 * ((size_t)1 << 23);          // 1<<24
    u16* Vt  = Xb;                                   // Xb dead after QKV GEMM

    prep_kernel<<<8960, 256, 0, stream>>>(X, Wq, Wk, Wv, Xb, Wt);
    qkv_gemm_kernel<<<768, 512, 0, stream>>>(Xb, Wt, QKV);
    s_tr_kernel<<<2624, 256, 0, stream>>>(QKV, S, Vt);
    softmax_kernel<<<2048, 256, 0, stream>>>(S);
    pv_gemm_kernel<<<256, 512, 0, stream>>>(S, Vt, out);
}